// Round 2
// baseline (1198.854 us; speedup 1.0000x reference)
//
#include <hip/hip_runtime.h>
#include <hip/hip_bf16.h>

#define N_NODES 50000
#define N_EDGES 800000
#define N_GRAPHS 64
#define HID 64

static inline size_t align256(size_t x) { return (x + 255) & ~(size_t)255; }

__global__ void zero_i32(int* __restrict__ p, int n) {
    int i = blockIdx.x * blockDim.x + threadIdx.x;
    if (i < n) p[i] = 0;
}

// count incoming edges per destination node
__global__ void deg_kernel(const int* __restrict__ ei, int* __restrict__ cnt) {
    int e = blockIdx.x * blockDim.x + threadIdx.x;
    if (e < N_EDGES) atomicAdd(&cnt[ei[N_EDGES + e]], 1);
}

// One-block scan over cnt -> row_ptr (exclusive+1), plus dinv and fill_ptr init.
// Each thread owns a 49-element contiguous chunk; one 10-step block scan of
// per-thread sums; serial writeback per chunk.
#define SCAN_CHUNK 49  // ceil(50000/1024)
__global__ __launch_bounds__(1024) void scan_kernel(const int* __restrict__ cnt,
                                                    int* __restrict__ row_ptr,
                                                    float* __restrict__ dinv,
                                                    int* __restrict__ fill_ptr) {
    __shared__ int ssum[1024];
    int tid = threadIdx.x;
    int start = tid * SCAN_CHUNK;
    int end = min(start + SCAN_CHUNK, N_NODES);
    int local = 0;
    for (int i = start; i < end; ++i) local += cnt[i];
    ssum[tid] = local;
    __syncthreads();
    for (int off = 1; off < 1024; off <<= 1) {
        int t = (tid >= off) ? ssum[tid - off] : 0;
        __syncthreads();
        ssum[tid] += t;
        __syncthreads();
    }
    int run = (tid > 0) ? ssum[tid - 1] : 0;  // exclusive prefix of this chunk
    for (int i = start; i < end; ++i) {
        int c = cnt[i];
        fill_ptr[i] = run;          // bucket start for fill_kernel
        run += c;
        row_ptr[i + 1] = run;
        dinv[i] = rsqrtf((float)c + 1.0f);
    }
    if (tid == 0) row_ptr[0] = 0;
}

// scatter edge sources into CSR buckets keyed by dst
__global__ void fill_kernel(const int* __restrict__ ei, int* __restrict__ fill_ptr,
                            int* __restrict__ csr_src) {
    int e = blockIdx.x * blockDim.x + threadIdx.x;
    if (e < N_EDGES) {
        int src = ei[e];
        int dst = ei[N_EDGES + e];
        int pos = atomicAdd(&fill_ptr[dst], 1);
        csr_src[pos] = src;
    }
}

// batch is sorted: find first node index with batch >= g, for g = 0..N_GRAPHS
__global__ void gstart_kernel(const int* __restrict__ batch, int* __restrict__ gstart) {
    int g = threadIdx.x;
    if (g <= N_GRAPHS) {
        int lo = 0, hi = N_NODES;
        while (lo < hi) {
            int mid = (lo + hi) >> 1;
            if (batch[mid] < g) lo = mid + 1; else hi = mid;
        }
        gstart[g] = lo;
    }
}

// hw2[row][col] = dinv[row] * sum_k h[row][k] * W[k][col]
// Block: 256 threads = 4 waves; wave computes 8 rows x 64 cols; block = 32 rows.
// W staged in LDS; h rows loaded as broadcast float4 (one cache line per wave).
template <int K>
__global__ __launch_bounds__(256) void matmul_kernel(const float* __restrict__ h,
                                                     const float* __restrict__ W,
                                                     const float* __restrict__ dinv,
                                                     float* __restrict__ hw2) {
    __shared__ float sW[K * 64];
    int tid = threadIdx.x;
    for (int i = tid * 4; i < K * 64; i += 256 * 4)
        *(float4*)&sW[i] = *(const float4*)&W[i];
    __syncthreads();

    int lane = tid & 63;
    int wid = tid >> 6;
    int row0 = blockIdx.x * 32 + wid * 8;

    float acc[8] = {0.f, 0.f, 0.f, 0.f, 0.f, 0.f, 0.f, 0.f};
    for (int k = 0; k < K; k += 4) {
        float4 hv[8];
#pragma unroll
        for (int r = 0; r < 8; ++r) {
            int row = min(row0 + r, N_NODES - 1);  // clamp: safe read, write guarded
            hv[r] = *(const float4*)&h[(size_t)row * K + k];
        }
#pragma unroll
        for (int kk = 0; kk < 4; ++kk) {
            float wv = sW[(k + kk) * 64 + lane];
#pragma unroll
            for (int r = 0; r < 8; ++r) {
                float hvk = (kk == 0) ? hv[r].x : (kk == 1) ? hv[r].y
                          : (kk == 2) ? hv[r].z : hv[r].w;
                acc[r] += hvk * wv;
            }
        }
    }
#pragma unroll
    for (int r = 0; r < 8; ++r) {
        int row = row0 + r;
        if (row < N_NODES) hw2[(size_t)row * 64 + lane] = dinv[row] * acc[r];
    }
}

// per node (one wave): val = dinv[i]*(sum_e hw2[src] + hw2[i]) + b
// then L2-normalize across 64 dims and ReLU.  (hw2 is pre-scaled by dinv[row])
__global__ __launch_bounds__(256) void agg_kernel(const float* __restrict__ hw2,
                                                  const int* __restrict__ row_ptr,
                                                  const int* __restrict__ csr_src,
                                                  const float* __restrict__ dinv,
                                                  const float* __restrict__ b,
                                                  float* __restrict__ hout) {
    int node = blockIdx.x * (blockDim.x >> 6) + (threadIdx.x >> 6);
    int lane = threadIdx.x & 63;
    if (node >= N_NODES) return;
    int s = row_ptr[node], e = row_ptr[node + 1];
    float acc = hw2[(size_t)node * 64 + lane];
    for (int idx = s; idx < e; ++idx) {
        int src = csr_src[idx];
        acc += hw2[(size_t)src * 64 + lane];
    }
    float val = dinv[node] * acc + b[lane];
    float sq = val * val;
#pragma unroll
    for (int off = 32; off >= 1; off >>= 1) sq += __shfl_xor(sq, off, 64);
    float nrm = sqrtf(sq);
    float r = val / fmaxf(nrm, 1e-12f);
    hout[(size_t)node * 64 + lane] = fmaxf(r, 0.f);
}

// one block per graph: mean+max pool over contiguous node range, then 128x32 linear
__global__ __launch_bounds__(256) void pool_linear_kernel(const float* __restrict__ h,
                                                          const int* __restrict__ gstart,
                                                          const float* __restrict__ Wl,
                                                          const float* __restrict__ bl,
                                                          float* __restrict__ out) {
    int g = blockIdx.x;
    int s = gstart[g], e = gstart[g + 1];
    int lane = threadIdx.x & 63;
    int wid = threadIdx.x >> 6;  // 0..3
    float sum = 0.f, mx = -3.4e38f;
    for (int i = s + wid; i < e; i += 4) {
        float v = h[(size_t)i * 64 + lane];
        sum += v;
        mx = fmaxf(mx, v);
    }
    __shared__ float ssum[4][64];
    __shared__ float smx[4][64];
    __shared__ float pooled[128];
    ssum[wid][lane] = sum;
    smx[wid][lane] = mx;
    __syncthreads();
    if (wid == 0) {
        float s4 = ssum[0][lane] + ssum[1][lane] + ssum[2][lane] + ssum[3][lane];
        float m4 = fmaxf(fmaxf(smx[0][lane], smx[1][lane]), fmaxf(smx[2][lane], smx[3][lane]));
        int cntg = e - s;
        float mean = s4 / fmaxf((float)cntg, 1.0f);
        if (cntg == 0) m4 = 0.f;
        pooled[lane] = mean;
        pooled[64 + lane] = m4;
    }
    __syncthreads();
    if (threadIdx.x < 32) {
        int j = threadIdx.x;
        float acc = bl[j];
#pragma unroll 8
        for (int k = 0; k < 128; ++k) acc += pooled[k] * Wl[k * 32 + j];
        out[g * 32 + j] = acc;
    }
}

extern "C" void kernel_launch(void* const* d_in, const int* in_sizes, int n_in,
                              void* d_out, int out_size, void* d_ws, size_t ws_size,
                              hipStream_t stream) {
    const float* x        = (const float*)d_in[0];   // 50000 x 128
    const int*   ei       = (const int*)d_in[1];     // 2 x 800000
    const int*   batch    = (const int*)d_in[2];     // 50000
    const float* W1       = (const float*)d_in[3];   // 128 x 64
    const float* b1       = (const float*)d_in[4];
    const float* W2       = (const float*)d_in[5];   // 64 x 64
    const float* b2       = (const float*)d_in[6];
    const float* W3       = (const float*)d_in[7];   // 64 x 64
    const float* b3       = (const float*)d_in[8];
    const float* Wl       = (const float*)d_in[9];   // 128 x 32
    const float* bl       = (const float*)d_in[10];
    float* out = (float*)d_out;

    char* ws = (char*)d_ws;
    int*   cnt      = (int*)ws;                 ws += align256((size_t)N_NODES * 4);
    int*   row_ptr  = (int*)ws;                 ws += align256((size_t)(N_NODES + 1) * 4);
    int*   fill_ptr = (int*)ws;                 ws += align256((size_t)N_NODES * 4);
    float* dinv     = (float*)ws;               ws += align256((size_t)N_NODES * 4);
    int*   gstart   = (int*)ws;                 ws += align256((size_t)(N_GRAPHS + 1) * 4);
    int*   csr_src  = (int*)ws;                 ws += align256((size_t)N_EDGES * 4);
    float* hwb      = (float*)ws;               ws += align256((size_t)N_NODES * 64 * 4);
    float* h1       = (float*)ws;               ws += align256((size_t)N_NODES * 64 * 4);
    float* h2       = (float*)ws;               ws += align256((size_t)N_NODES * 64 * 4);

    hipLaunchKernelGGL(zero_i32, dim3((N_NODES + 255) / 256), dim3(256), 0, stream, cnt, N_NODES);
    hipLaunchKernelGGL(deg_kernel, dim3((N_EDGES + 255) / 256), dim3(256), 0, stream, ei, cnt);
    hipLaunchKernelGGL(scan_kernel, dim3(1), dim3(1024), 0, stream, cnt, row_ptr, dinv, fill_ptr);
    hipLaunchKernelGGL(fill_kernel, dim3((N_EDGES + 255) / 256), dim3(256), 0, stream,
                       ei, fill_ptr, csr_src);
    hipLaunchKernelGGL(gstart_kernel, dim3(1), dim3(128), 0, stream, batch, gstart);

    const int mm_grid = (N_NODES + 31) / 32;
    const int agg_grid = (N_NODES + 3) / 4;  // 4 waves per block, wave per node

    // layer 1: x(128) @ W1 -> hw2 (dinv-scaled); agg -> h1
    hipLaunchKernelGGL((matmul_kernel<128>), dim3(mm_grid), dim3(256), 0, stream, x, W1, dinv, hwb);
    hipLaunchKernelGGL(agg_kernel, dim3(agg_grid), dim3(256), 0, stream,
                       hwb, row_ptr, csr_src, dinv, b1, h1);
    // layer 2
    hipLaunchKernelGGL((matmul_kernel<64>), dim3(mm_grid), dim3(256), 0, stream, h1, W2, dinv, hwb);
    hipLaunchKernelGGL(agg_kernel, dim3(agg_grid), dim3(256), 0, stream,
                       hwb, row_ptr, csr_src, dinv, b2, h2);
    // layer 3
    hipLaunchKernelGGL((matmul_kernel<64>), dim3(mm_grid), dim3(256), 0, stream, h2, W3, dinv, hwb);
    hipLaunchKernelGGL(agg_kernel, dim3(agg_grid), dim3(256), 0, stream,
                       hwb, row_ptr, csr_src, dinv, b3, h1);

    // pooling + final linear
    hipLaunchKernelGGL(pool_linear_kernel, dim3(N_GRAPHS), dim3(256), 0, stream,
                       h1, gstart, Wl, bl, out);
}

// Round 3
// 642.155 us; speedup vs baseline: 1.8669x; 1.8669x over previous
//
#include <hip/hip_runtime.h>
#include <hip/hip_bf16.h>

#define N_NODES 50000
#define N_EDGES 800000
#define N_GRAPHS 64
#define HID 64

static inline size_t align256(size_t x) { return (x + 255) & ~(size_t)255; }

__global__ void zero_i32(int* __restrict__ p, int n) {
    int i = blockIdx.x * blockDim.x + threadIdx.x;
    if (i < n) p[i] = 0;
}

// count incoming edges per destination node
__global__ void deg_kernel(const int* __restrict__ ei, int* __restrict__ cnt) {
    int e = blockIdx.x * blockDim.x + threadIdx.x;
    if (e < N_EDGES) atomicAdd(&cnt[ei[N_EDGES + e]], 1);
}

// One-block scan over cnt -> row_ptr (exclusive+1), plus dinv and fill_ptr init.
#define SCAN_CHUNK 49  // ceil(50000/1024)
__global__ __launch_bounds__(1024) void scan_kernel(const int* __restrict__ cnt,
                                                    int* __restrict__ row_ptr,
                                                    float* __restrict__ dinv,
                                                    int* __restrict__ fill_ptr) {
    __shared__ int ssum[1024];
    int tid = threadIdx.x;
    int start = tid * SCAN_CHUNK;
    int end = min(start + SCAN_CHUNK, N_NODES);
    int local = 0;
    for (int i = start; i < end; ++i) local += cnt[i];
    ssum[tid] = local;
    __syncthreads();
    for (int off = 1; off < 1024; off <<= 1) {
        int t = (tid >= off) ? ssum[tid - off] : 0;
        __syncthreads();
        ssum[tid] += t;
        __syncthreads();
    }
    int run = (tid > 0) ? ssum[tid - 1] : 0;  // exclusive prefix of this chunk
    for (int i = start; i < end; ++i) {
        int c = cnt[i];
        fill_ptr[i] = run;          // bucket start for fill_kernel
        run += c;
        row_ptr[i + 1] = run;
        dinv[i] = rsqrtf((float)c + 1.0f);
    }
    if (tid == 0) row_ptr[0] = 0;
}

// scatter edge sources into CSR buckets keyed by dst
__global__ void fill_kernel(const int* __restrict__ ei, int* __restrict__ fill_ptr,
                            int* __restrict__ csr_src) {
    int e = blockIdx.x * blockDim.x + threadIdx.x;
    if (e < N_EDGES) {
        int src = ei[e];
        int dst = ei[N_EDGES + e];
        int pos = atomicAdd(&fill_ptr[dst], 1);
        csr_src[pos] = src;
    }
}

// batch is sorted: find first node index with batch >= g, for g = 0..N_GRAPHS
__global__ void gstart_kernel(const int* __restrict__ batch, int* __restrict__ gstart) {
    int g = threadIdx.x;
    if (g <= N_GRAPHS) {
        int lo = 0, hi = N_NODES;
        while (lo < hi) {
            int mid = (lo + hi) >> 1;
            if (batch[mid] < g) lo = mid + 1; else hi = mid;
        }
        gstart[g] = lo;
    }
}

// hw2[row][col] = dinv[row] * sum_k h[row][k] * W[k][col]
// 256 threads = 4 waves; wave computes 4 rows x 64 cols; block = 16 rows.
// W staged in LDS; h rows loaded as broadcast float4.
// k-loop pinned at unroll 1 to prevent register-spill explosion (round-2 lesson:
// full unroll -> 256 VGPR + 1.3 GB scratch traffic).
template <int K>
__global__ __launch_bounds__(256) void matmul_kernel(const float* __restrict__ h,
                                                     const float* __restrict__ W,
                                                     const float* __restrict__ dinv,
                                                     float* __restrict__ hw2) {
    __shared__ float sW[K * 64];
    int tid = threadIdx.x;
#pragma unroll 1
    for (int i = tid * 4; i < K * 64; i += 256 * 4)
        *(float4*)&sW[i] = *(const float4*)&W[i];
    __syncthreads();

    int lane = tid & 63;
    int wid = tid >> 6;
    int row0 = blockIdx.x * 16 + wid * 4;

    float acc0 = 0.f, acc1 = 0.f, acc2 = 0.f, acc3 = 0.f;
#pragma unroll 1
    for (int k = 0; k < K; k += 4) {
        int r0 = min(row0 + 0, N_NODES - 1);
        int r1 = min(row0 + 1, N_NODES - 1);
        int r2 = min(row0 + 2, N_NODES - 1);
        int r3 = min(row0 + 3, N_NODES - 1);
        float4 h0 = *(const float4*)&h[(size_t)r0 * K + k];
        float4 h1 = *(const float4*)&h[(size_t)r1 * K + k];
        float4 h2 = *(const float4*)&h[(size_t)r2 * K + k];
        float4 h3 = *(const float4*)&h[(size_t)r3 * K + k];
        float w0 = sW[(k + 0) * 64 + lane];
        float w1 = sW[(k + 1) * 64 + lane];
        float w2 = sW[(k + 2) * 64 + lane];
        float w3 = sW[(k + 3) * 64 + lane];
        acc0 += h0.x * w0 + h0.y * w1 + h0.z * w2 + h0.w * w3;
        acc1 += h1.x * w0 + h1.y * w1 + h1.z * w2 + h1.w * w3;
        acc2 += h2.x * w0 + h2.y * w1 + h2.z * w2 + h2.w * w3;
        acc3 += h3.x * w0 + h3.y * w1 + h3.z * w2 + h3.w * w3;
    }
    float accs[4] = {acc0, acc1, acc2, acc3};
#pragma unroll
    for (int r = 0; r < 4; ++r) {
        int row = row0 + r;
        if (row < N_NODES) hw2[(size_t)row * 64 + lane] = dinv[row] * accs[r];
    }
}

// per node (one wave): val = dinv[i]*(sum_e hw2[src] + hw2[i]) + b
// then L2-normalize across 64 dims and ReLU.  (hw2 is pre-scaled by dinv[row])
__global__ __launch_bounds__(256) void agg_kernel(const float* __restrict__ hw2,
                                                  const int* __restrict__ row_ptr,
                                                  const int* __restrict__ csr_src,
                                                  const float* __restrict__ dinv,
                                                  const float* __restrict__ b,
                                                  float* __restrict__ hout) {
    int node = blockIdx.x * (blockDim.x >> 6) + (threadIdx.x >> 6);
    int lane = threadIdx.x & 63;
    if (node >= N_NODES) return;
    int s = row_ptr[node], e = row_ptr[node + 1];
    float acc = hw2[(size_t)node * 64 + lane];
    for (int idx = s; idx < e; ++idx) {
        int src = csr_src[idx];
        acc += hw2[(size_t)src * 64 + lane];
    }
    float val = dinv[node] * acc + b[lane];
    float sq = val * val;
#pragma unroll
    for (int off = 32; off >= 1; off >>= 1) sq += __shfl_xor(sq, off, 64);
    float nrm = sqrtf(sq);
    float r = val / fmaxf(nrm, 1e-12f);
    hout[(size_t)node * 64 + lane] = fmaxf(r, 0.f);
}

// one block per graph: mean+max pool over contiguous node range, then 128x32 linear
__global__ __launch_bounds__(256) void pool_linear_kernel(const float* __restrict__ h,
                                                          const int* __restrict__ gstart,
                                                          const float* __restrict__ Wl,
                                                          const float* __restrict__ bl,
                                                          float* __restrict__ out) {
    int g = blockIdx.x;
    int s = gstart[g], e = gstart[g + 1];
    int lane = threadIdx.x & 63;
    int wid = threadIdx.x >> 6;  // 0..3
    float sum = 0.f, mx = -3.4e38f;
    for (int i = s + wid; i < e; i += 4) {
        float v = h[(size_t)i * 64 + lane];
        sum += v;
        mx = fmaxf(mx, v);
    }
    __shared__ float ssum[4][64];
    __shared__ float smx[4][64];
    __shared__ float pooled[128];
    ssum[wid][lane] = sum;
    smx[wid][lane] = mx;
    __syncthreads();
    if (wid == 0) {
        float s4 = ssum[0][lane] + ssum[1][lane] + ssum[2][lane] + ssum[3][lane];
        float m4 = fmaxf(fmaxf(smx[0][lane], smx[1][lane]), fmaxf(smx[2][lane], smx[3][lane]));
        int cntg = e - s;
        float mean = s4 / fmaxf((float)cntg, 1.0f);
        if (cntg == 0) m4 = 0.f;
        pooled[lane] = mean;
        pooled[64 + lane] = m4;
    }
    __syncthreads();
    if (threadIdx.x < 32) {
        int j = threadIdx.x;
        float acc = bl[j];
#pragma unroll 8
        for (int k = 0; k < 128; ++k) acc += pooled[k] * Wl[k * 32 + j];
        out[g * 32 + j] = acc;
    }
}

extern "C" void kernel_launch(void* const* d_in, const int* in_sizes, int n_in,
                              void* d_out, int out_size, void* d_ws, size_t ws_size,
                              hipStream_t stream) {
    const float* x        = (const float*)d_in[0];   // 50000 x 128
    const int*   ei       = (const int*)d_in[1];     // 2 x 800000
    const int*   batch    = (const int*)d_in[2];     // 50000
    const float* W1       = (const float*)d_in[3];   // 128 x 64
    const float* b1       = (const float*)d_in[4];
    const float* W2       = (const float*)d_in[5];   // 64 x 64
    const float* b2       = (const float*)d_in[6];
    const float* W3       = (const float*)d_in[7];   // 64 x 64
    const float* b3       = (const float*)d_in[8];
    const float* Wl       = (const float*)d_in[9];   // 128 x 32
    const float* bl       = (const float*)d_in[10];
    float* out = (float*)d_out;

    char* ws = (char*)d_ws;
    int*   cnt      = (int*)ws;                 ws += align256((size_t)N_NODES * 4);
    int*   row_ptr  = (int*)ws;                 ws += align256((size_t)(N_NODES + 1) * 4);
    int*   fill_ptr = (int*)ws;                 ws += align256((size_t)N_NODES * 4);
    float* dinv     = (float*)ws;               ws += align256((size_t)N_NODES * 4);
    int*   gstart   = (int*)ws;                 ws += align256((size_t)(N_GRAPHS + 1) * 4);
    int*   csr_src  = (int*)ws;                 ws += align256((size_t)N_EDGES * 4);
    float* hwb      = (float*)ws;               ws += align256((size_t)N_NODES * 64 * 4);
    float* h1       = (float*)ws;               ws += align256((size_t)N_NODES * 64 * 4);
    float* h2       = (float*)ws;               ws += align256((size_t)N_NODES * 64 * 4);

    hipLaunchKernelGGL(zero_i32, dim3((N_NODES + 255) / 256), dim3(256), 0, stream, cnt, N_NODES);
    hipLaunchKernelGGL(deg_kernel, dim3((N_EDGES + 255) / 256), dim3(256), 0, stream, ei, cnt);
    hipLaunchKernelGGL(scan_kernel, dim3(1), dim3(1024), 0, stream, cnt, row_ptr, dinv, fill_ptr);
    hipLaunchKernelGGL(fill_kernel, dim3((N_EDGES + 255) / 256), dim3(256), 0, stream,
                       ei, fill_ptr, csr_src);
    hipLaunchKernelGGL(gstart_kernel, dim3(1), dim3(128), 0, stream, batch, gstart);

    const int mm_grid = (N_NODES + 15) / 16;
    const int agg_grid = (N_NODES + 3) / 4;  // 4 waves per block, wave per node

    // layer 1: x(128) @ W1 -> hw2 (dinv-scaled); agg -> h1
    hipLaunchKernelGGL((matmul_kernel<128>), dim3(mm_grid), dim3(256), 0, stream, x, W1, dinv, hwb);
    hipLaunchKernelGGL(agg_kernel, dim3(agg_grid), dim3(256), 0, stream,
                       hwb, row_ptr, csr_src, dinv, b1, h1);
    // layer 2
    hipLaunchKernelGGL((matmul_kernel<64>), dim3(mm_grid), dim3(256), 0, stream, h1, W2, dinv, hwb);
    hipLaunchKernelGGL(agg_kernel, dim3(agg_grid), dim3(256), 0, stream,
                       hwb, row_ptr, csr_src, dinv, b2, h2);
    // layer 3
    hipLaunchKernelGGL((matmul_kernel<64>), dim3(mm_grid), dim3(256), 0, stream, h2, W3, dinv, hwb);
    hipLaunchKernelGGL(agg_kernel, dim3(agg_grid), dim3(256), 0, stream,
                       hwb, row_ptr, csr_src, dinv, b3, h1);

    // pooling + final linear
    hipLaunchKernelGGL(pool_linear_kernel, dim3(N_GRAPHS), dim3(256), 0, stream,
                       h1, gstart, Wl, bl, out);
}

// Round 4
// 392.246 us; speedup vs baseline: 3.0564x; 1.6371x over previous
//
#include <hip/hip_runtime.h>
#include <hip/hip_bf16.h>

#define N_NODES 50000
#define N_EDGES 800000
#define N_GRAPHS 64
#define HID 64
#define SCAN_NB 196  // ceil(50000/256)

static inline size_t align256(size_t x) { return (x + 255) & ~(size_t)255; }

__global__ void zero_i32(int* __restrict__ p, int n) {
    int i = blockIdx.x * blockDim.x + threadIdx.x;
    if (i < n) p[i] = 0;
}

// count incoming edges per destination node
__global__ void deg_kernel(const int* __restrict__ ei, int* __restrict__ cnt) {
    int e = blockIdx.x * blockDim.x + threadIdx.x;
    if (e < N_EDGES) atomicAdd(&cnt[ei[N_EDGES + e]], 1);
}

// phase A: per-block (256-wide) inclusive scan of cnt; block totals to bsum
__global__ __launch_bounds__(256) void scan_a(const int* __restrict__ cnt,
                                              int* __restrict__ incl,
                                              int* __restrict__ bsum) {
    __shared__ int sd[256];
    int t = threadIdx.x;
    int i = blockIdx.x * 256 + t;
    int v = (i < N_NODES) ? cnt[i] : 0;
    sd[t] = v;
    __syncthreads();
    for (int off = 1; off < 256; off <<= 1) {
        int u = (t >= off) ? sd[t - off] : 0;
        __syncthreads();
        sd[t] += u;
        __syncthreads();
    }
    if (i < N_NODES) incl[i] = sd[t];
    if (t == 255) bsum[blockIdx.x] = sd[255];
}

// phase B: single block, exclusive scan of the 196 block sums
__global__ __launch_bounds__(256) void scan_b(const int* __restrict__ bsum,
                                              int* __restrict__ boff) {
    __shared__ int sd[256];
    int t = threadIdx.x;
    int v = (t < SCAN_NB) ? bsum[t] : 0;
    sd[t] = v;
    __syncthreads();
    for (int off = 1; off < 256; off <<= 1) {
        int u = (t >= off) ? sd[t - off] : 0;
        __syncthreads();
        sd[t] += u;
        __syncthreads();
    }
    if (t < SCAN_NB) boff[t] = sd[t] - v;  // exclusive
}

// phase C: writeback row_ptr / fill_ptr / dinv
__global__ void scan_c(const int* __restrict__ cnt, const int* __restrict__ incl,
                       const int* __restrict__ boff, int* __restrict__ row_ptr,
                       int* __restrict__ fill_ptr, float* __restrict__ dinv) {
    int i = blockIdx.x * blockDim.x + threadIdx.x;
    if (i < N_NODES) {
        int c = cnt[i];
        int run = boff[i >> 8] + incl[i];  // inclusive prefix over all nodes
        row_ptr[i + 1] = run;
        fill_ptr[i] = run - c;             // bucket start
        dinv[i] = rsqrtf((float)c + 1.0f);
        if (i == 0) row_ptr[0] = 0;
    }
}

// scatter edge sources into CSR buckets keyed by dst
__global__ void fill_kernel(const int* __restrict__ ei, int* __restrict__ fill_ptr,
                            int* __restrict__ csr_src) {
    int e = blockIdx.x * blockDim.x + threadIdx.x;
    if (e < N_EDGES) {
        int src = ei[e];
        int dst = ei[N_EDGES + e];
        int pos = atomicAdd(&fill_ptr[dst], 1);
        csr_src[pos] = src;
    }
}

// batch is sorted: find first node index with batch >= g, for g = 0..N_GRAPHS
__global__ void gstart_kernel(const int* __restrict__ batch, int* __restrict__ gstart) {
    int g = threadIdx.x;
    if (g <= N_GRAPHS) {
        int lo = 0, hi = N_NODES;
        while (lo < hi) {
            int mid = (lo + hi) >> 1;
            if (batch[mid] < g) lo = mid + 1; else hi = mid;
        }
        gstart[g] = lo;
    }
}

// hw2[row][col] = dinv[row] * sum_k h[row][k] * W[k][col]
// 256 threads = 4 waves; wave computes 4 rows x 64 cols; block = 16 rows.
// k-loop pinned at unroll 1 (round-2 lesson: full unroll -> 256 VGPR + spills).
template <int K>
__global__ __launch_bounds__(256) void matmul_kernel(const float* __restrict__ h,
                                                     const float* __restrict__ W,
                                                     const float* __restrict__ dinv,
                                                     float* __restrict__ hw2) {
    __shared__ float sW[K * 64];
    int tid = threadIdx.x;
#pragma unroll 1
    for (int i = tid * 4; i < K * 64; i += 256 * 4)
        *(float4*)&sW[i] = *(const float4*)&W[i];
    __syncthreads();

    int lane = tid & 63;
    int wid = tid >> 6;
    int row0 = blockIdx.x * 16 + wid * 4;

    float acc0 = 0.f, acc1 = 0.f, acc2 = 0.f, acc3 = 0.f;
#pragma unroll 1
    for (int k = 0; k < K; k += 4) {
        int r0 = min(row0 + 0, N_NODES - 1);
        int r1 = min(row0 + 1, N_NODES - 1);
        int r2 = min(row0 + 2, N_NODES - 1);
        int r3 = min(row0 + 3, N_NODES - 1);
        float4 h0 = *(const float4*)&h[(size_t)r0 * K + k];
        float4 h1 = *(const float4*)&h[(size_t)r1 * K + k];
        float4 h2 = *(const float4*)&h[(size_t)r2 * K + k];
        float4 h3 = *(const float4*)&h[(size_t)r3 * K + k];
        float w0 = sW[(k + 0) * 64 + lane];
        float w1 = sW[(k + 1) * 64 + lane];
        float w2 = sW[(k + 2) * 64 + lane];
        float w3 = sW[(k + 3) * 64 + lane];
        acc0 += h0.x * w0 + h0.y * w1 + h0.z * w2 + h0.w * w3;
        acc1 += h1.x * w0 + h1.y * w1 + h1.z * w2 + h1.w * w3;
        acc2 += h2.x * w0 + h2.y * w1 + h2.z * w2 + h2.w * w3;
        acc3 += h3.x * w0 + h3.y * w1 + h3.z * w2 + h3.w * w3;
    }
    float accs[4] = {acc0, acc1, acc2, acc3};
#pragma unroll
    for (int r = 0; r < 4; ++r) {
        int row = row0 + r;
        if (row < N_NODES) hw2[(size_t)row * 64 + lane] = dinv[row] * accs[r];
    }
}

// per node (one wave): 4 edges in flight per iteration.
// lane = 16*grp + gl; each 16-lane group fetches a full 256B row as float4s.
// Cross-group reduce via shfl_xor(16,32); group 0 writes the result.
__global__ __launch_bounds__(256) void agg_kernel(const float* __restrict__ hw2,
                                                  const int* __restrict__ row_ptr,
                                                  const int* __restrict__ csr_src,
                                                  const float* __restrict__ dinv,
                                                  const float* __restrict__ b,
                                                  float* __restrict__ hout) {
    int node = blockIdx.x * 4 + (threadIdx.x >> 6);
    int lane = threadIdx.x & 63;
    if (node >= N_NODES) return;
    int grp = lane >> 4;   // 0..3 : which edge of the 4-wide batch
    int gl  = lane & 15;   // 0..15: which float4 of the row
    int s = row_ptr[node], e = row_ptr[node + 1];

    float ax = 0.f, ay = 0.f, az = 0.f, aw = 0.f;
    for (int idx = s + grp; idx < e; idx += 4) {
        int src = csr_src[idx];
        float4 v = *(const float4*)&hw2[(size_t)src * 64 + gl * 4];
        ax += v.x; ay += v.y; az += v.z; aw += v.w;
    }
    // sum the 4 groups' partials (dims are aligned across groups)
#pragma unroll
    for (int off = 16; off <= 32; off <<= 1) {
        ax += __shfl_xor(ax, off, 64);
        ay += __shfl_xor(ay, off, 64);
        az += __shfl_xor(az, off, 64);
        aw += __shfl_xor(aw, off, 64);
    }
    // self-loop term (hw2 pre-scaled by dinv[row])
    float4 self = *(const float4*)&hw2[(size_t)node * 64 + gl * 4];
    ax += self.x; ay += self.y; az += self.z; aw += self.w;

    float di = dinv[node];
    float4 bb = *(const float4*)&b[gl * 4];
    float vx = di * ax + bb.x;
    float vy = di * ay + bb.y;
    float vz = di * az + bb.z;
    float vw = di * aw + bb.w;

    float sq = vx * vx + vy * vy + vz * vz + vw * vw;
#pragma unroll
    for (int off = 1; off <= 8; off <<= 1) sq += __shfl_xor(sq, off, 64);
    float inv = 1.0f / fmaxf(sqrtf(sq), 1e-12f);

    if (grp == 0) {
        float4 r;
        r.x = fmaxf(vx * inv, 0.f);
        r.y = fmaxf(vy * inv, 0.f);
        r.z = fmaxf(vz * inv, 0.f);
        r.w = fmaxf(vw * inv, 0.f);
        *(float4*)&hout[(size_t)node * 64 + gl * 4] = r;
    }
}

// one block per graph: mean+max pool over contiguous node range, then 128x32 linear
__global__ __launch_bounds__(256) void pool_linear_kernel(const float* __restrict__ h,
                                                          const int* __restrict__ gstart,
                                                          const float* __restrict__ Wl,
                                                          const float* __restrict__ bl,
                                                          float* __restrict__ out) {
    int g = blockIdx.x;
    int s = gstart[g], e = gstart[g + 1];
    int lane = threadIdx.x & 63;
    int wid = threadIdx.x >> 6;  // 0..3
    float sum = 0.f, mx = -3.4e38f;
    for (int i = s + wid; i < e; i += 4) {
        float v = h[(size_t)i * 64 + lane];
        sum += v;
        mx = fmaxf(mx, v);
    }
    __shared__ float ssum[4][64];
    __shared__ float smx[4][64];
    __shared__ float pooled[128];
    ssum[wid][lane] = sum;
    smx[wid][lane] = mx;
    __syncthreads();
    if (wid == 0) {
        float s4 = ssum[0][lane] + ssum[1][lane] + ssum[2][lane] + ssum[3][lane];
        float m4 = fmaxf(fmaxf(smx[0][lane], smx[1][lane]), fmaxf(smx[2][lane], smx[3][lane]));
        int cntg = e - s;
        float mean = s4 / fmaxf((float)cntg, 1.0f);
        if (cntg == 0) m4 = 0.f;
        pooled[lane] = mean;
        pooled[64 + lane] = m4;
    }
    __syncthreads();
    if (threadIdx.x < 32) {
        int j = threadIdx.x;
        float acc = bl[j];
#pragma unroll 8
        for (int k = 0; k < 128; ++k) acc += pooled[k] * Wl[k * 32 + j];
        out[g * 32 + j] = acc;
    }
}

extern "C" void kernel_launch(void* const* d_in, const int* in_sizes, int n_in,
                              void* d_out, int out_size, void* d_ws, size_t ws_size,
                              hipStream_t stream) {
    const float* x        = (const float*)d_in[0];   // 50000 x 128
    const int*   ei       = (const int*)d_in[1];     // 2 x 800000
    const int*   batch    = (const int*)d_in[2];     // 50000
    const float* W1       = (const float*)d_in[3];   // 128 x 64
    const float* b1       = (const float*)d_in[4];
    const float* W2       = (const float*)d_in[5];   // 64 x 64
    const float* b2       = (const float*)d_in[6];
    const float* W3       = (const float*)d_in[7];   // 64 x 64
    const float* b3       = (const float*)d_in[8];
    const float* Wl       = (const float*)d_in[9];   // 128 x 32
    const float* bl       = (const float*)d_in[10];
    float* out = (float*)d_out;

    char* ws = (char*)d_ws;
    int*   cnt      = (int*)ws;                 ws += align256((size_t)N_NODES * 4);
    int*   incl     = (int*)ws;                 ws += align256((size_t)N_NODES * 4);
    int*   bsum     = (int*)ws;                 ws += align256((size_t)SCAN_NB * 4);
    int*   boff     = (int*)ws;                 ws += align256((size_t)SCAN_NB * 4);
    int*   row_ptr  = (int*)ws;                 ws += align256((size_t)(N_NODES + 1) * 4);
    int*   fill_ptr = (int*)ws;                 ws += align256((size_t)N_NODES * 4);
    float* dinv     = (float*)ws;               ws += align256((size_t)N_NODES * 4);
    int*   gstart   = (int*)ws;                 ws += align256((size_t)(N_GRAPHS + 1) * 4);
    int*   csr_src  = (int*)ws;                 ws += align256((size_t)N_EDGES * 4);
    float* hwb      = (float*)ws;               ws += align256((size_t)N_NODES * 64 * 4);
    float* h1       = (float*)ws;               ws += align256((size_t)N_NODES * 64 * 4);
    float* h2       = (float*)ws;               ws += align256((size_t)N_NODES * 64 * 4);

    hipLaunchKernelGGL(zero_i32, dim3((N_NODES + 255) / 256), dim3(256), 0, stream, cnt, N_NODES);
    hipLaunchKernelGGL(deg_kernel, dim3((N_EDGES + 255) / 256), dim3(256), 0, stream, ei, cnt);
    hipLaunchKernelGGL(scan_a, dim3(SCAN_NB), dim3(256), 0, stream, cnt, incl, bsum);
    hipLaunchKernelGGL(scan_b, dim3(1), dim3(256), 0, stream, bsum, boff);
    hipLaunchKernelGGL(scan_c, dim3(SCAN_NB), dim3(256), 0, stream,
                       cnt, incl, boff, row_ptr, fill_ptr, dinv);
    hipLaunchKernelGGL(fill_kernel, dim3((N_EDGES + 255) / 256), dim3(256), 0, stream,
                       ei, fill_ptr, csr_src);
    hipLaunchKernelGGL(gstart_kernel, dim3(1), dim3(128), 0, stream, batch, gstart);

    const int mm_grid = (N_NODES + 15) / 16;
    const int agg_grid = (N_NODES + 3) / 4;  // 4 waves per block, wave per node

    // layer 1: x(128) @ W1 -> hw2 (dinv-scaled); agg -> h1
    hipLaunchKernelGGL((matmul_kernel<128>), dim3(mm_grid), dim3(256), 0, stream, x, W1, dinv, hwb);
    hipLaunchKernelGGL(agg_kernel, dim3(agg_grid), dim3(256), 0, stream,
                       hwb, row_ptr, csr_src, dinv, b1, h1);
    // layer 2
    hipLaunchKernelGGL((matmul_kernel<64>), dim3(mm_grid), dim3(256), 0, stream, h1, W2, dinv, hwb);
    hipLaunchKernelGGL(agg_kernel, dim3(agg_grid), dim3(256), 0, stream,
                       hwb, row_ptr, csr_src, dinv, b2, h2);
    // layer 3
    hipLaunchKernelGGL((matmul_kernel<64>), dim3(mm_grid), dim3(256), 0, stream, h2, W3, dinv, hwb);
    hipLaunchKernelGGL(agg_kernel, dim3(agg_grid), dim3(256), 0, stream,
                       hwb, row_ptr, csr_src, dinv, b3, h1);

    // pooling + final linear
    hipLaunchKernelGGL(pool_linear_kernel, dim3(N_GRAPHS), dim3(256), 0, stream,
                       h1, gstart, Wl, bl, out);
}